// Round 18
// baseline (394.836 us; speedup 1.0000x reference)
//
#include <hip/hip_runtime.h>
#include <hip/hip_bf16.h>

// DRew-GIN: N=50000, E=800000, D=128, L=3, NU=1.
// R21 (315.8us, proven best): discrete front-end (km1-major) + identity
//   worklist + R12 gather/lgemm bodies. 11 launches.
// R25 column-sliced gather: REJECTED (344.7us) — L2 residency didn't
//   materialize (57% miss even at 3.2MB slices); gather is L3-transaction
//   bound, near floor (~80us total).
// R27 gather (256,8): NULL (316.9) — not occupancy-capped. Reverted to (256,6).
// R28: front-end compaction, same math:
//   (a) hipMemsetAsync zeroes cursor;
//   (b) hist fused into init (block-range split);
//   (c) scan_a+scanc fused (per-block direct global prefix; fill-cursor in
//       separate cur2 array to avoid read/write race);
//   (d) fill single-pass (NPART=1, -19MB re-reads).
//   10 dispatches: memset|init_hist|scan|fill|gatherA|lgemm0|gatherB|lgemm1|gatherC|lgemm2.

#define NODES 50000
#define EDGES 800000
#define DIM   128
#define ND    ((long)NODES * DIM)
#define NB3   (3 * NODES)            // buckets: km1*NODES + d
#define NROWP 50048                  // row-padded tensors (tail tile slack)
#define NBLKS ((NB3 + 255) / 256)    // 587
#define EGRID ((EDGES + 255) / 256)  // 3125
#define CGRID ((int)(ND / 4 / 256))  // 6250 conversion blocks

typedef __attribute__((ext_vector_type(8))) short  bf16x8;
typedef __attribute__((ext_vector_type(4))) float  f32x4;

#define LDS_STRIDE 136   // bf16 elements; 272B rows

// ---------------------------------------------------------------------------
// Fused init + hist. cursor must be pre-zeroed (memset).
// Block ranges: [0,6250) x->bf16 | [6250,6262) weights | [6262,6264) dummy
// rows | [6264, 6264+EGRID) histogram.
__global__ __launch_bounds__(256) void init_hist_kernel(
    const float* __restrict__ x, const float* __restrict__ Ws,
    const float* __restrict__ Wk, __hip_bfloat16* __restrict__ xb0,
    __hip_bfloat16* __restrict__ xb1, __hip_bfloat16* __restrict__ xb2,
    __hip_bfloat16* __restrict__ WT,
    const int* __restrict__ ei, const int* __restrict__ attr,
    int* __restrict__ cursor) {
  int b = blockIdx.x, tid = threadIdx.x;
  if (b < CGRID) {
    long i = (long)b * 256 + tid;          // < ND/4 exactly
    float4 v = ((const float4*)x)[i];
    union { __hip_bfloat16 h[4]; uint2 u; } pk;
    pk.h[0] = __float2bfloat16(v.x); pk.h[1] = __float2bfloat16(v.y);
    pk.h[2] = __float2bfloat16(v.z); pk.h[3] = __float2bfloat16(v.w);
    ((uint2*)xb0)[i] = pk.u;
  } else if (b < CGRID + 12) {
    int wb = b - CGRID;
    const float* src = (wb < 3) ? (Ws + (long)wb * 16384) : (Wk + (long)(wb - 3) * 16384);
    __hip_bfloat16* dst = WT + (long)wb * 16384;
    for (int idx = tid; idx < 16384; idx += 256) {
      int k = idx >> 7, n = idx & 127;
      dst[n * 128 + k] = __float2bfloat16(src[idx]);
    }
  } else if (b < CGRID + 14) {
    int g = (b - (CGRID + 12)) * 256 + tid;
    if (g < 3 * DIM) {
      int which = g >> 7, dcol = g & 127;
      __hip_bfloat16* xb = (which == 0) ? xb0 : ((which == 1) ? xb1 : xb2);
      xb[(long)NODES * DIM + dcol] = __float2bfloat16(0.f);
    }
  } else {
    int e = (b - (CGRID + 14)) * 256 + tid;
    if (e < EDGES)
      atomicAdd(&cursor[(attr[e] - 1) * NODES + ei[EDGES + e]], 1);
  }
}

// ---------------------------------------------------------------------------
// Fused scan: each block computes its global exclusive prefix directly
// (sum of ALL preceding padded counts; cursor is READ-ONLY here), local
// scan, writes rowptr + cur2 (fill cursor) + csr pad-slack.
__global__ __launch_bounds__(256) void scan_kernel(
    const int* __restrict__ cursor, int* __restrict__ rowptr,
    int* __restrict__ cur2, int* __restrict__ csr, int n) {
  __shared__ int red[256];
  __shared__ int tmp[256];
  int tid = threadIdx.x;
  int limit = blockIdx.x * 256;
  int partial = 0;
  for (int i = tid; i < limit; i += 256) partial += (cursor[i] + 3) & ~3;
  red[tid] = partial;
  __syncthreads();
  for (int off = 128; off > 0; off >>= 1) {
    if (tid < off) red[tid] += red[tid + off];
    __syncthreads();
  }
  int bsoff = red[0];
  int gid = limit + tid;
  int cnt = (gid < n) ? cursor[gid] : 0;
  int pv = (cnt + 3) & ~3;
  tmp[tid] = pv;
  __syncthreads();
  for (int off = 1; off < 256; off <<= 1) {
    int t = (tid >= off) ? tmp[tid - off] : 0;
    __syncthreads();
    tmp[tid] += t;
    __syncthreads();
  }
  if (gid < n) {
    int val = tmp[tid] - pv + bsoff;
    rowptr[gid] = val;
    cur2[gid] = val;
    for (int i = cnt; i < pv; ++i) csr[val + i] = NODES;
    if (gid == n - 1) rowptr[n] = val + pv;
  }
}

// Single-pass fill (scattered atomics on cur2; ~5 edges/bucket contention).
__global__ __launch_bounds__(256) void fill_kernel(
    const int* __restrict__ ei, const int* __restrict__ attr,
    int* __restrict__ cur2, int* __restrict__ csr_src, int E) {
  int e = blockIdx.x * 256 + threadIdx.x;
  if (e >= E) return;
  int pos = atomicAdd(&cur2[(attr[e] - 1) * NODES + ei[E + e]], 1);
  csr_src[pos] = ei[e];
}

// ---------------------------------------------------------------------------
// Gather (R21/R12 body, identity worklist, (256,6) proven config).
__global__ __launch_bounds__(256, 6) void gather_kernel(
    const __hip_bfloat16* __restrict__ src,
    const int* __restrict__ rowptr, const int* __restrict__ csr,
    __hip_bfloat16* __restrict__ ag0, __hip_bfloat16* __restrict__ ag1,
    __hip_bfloat16* __restrict__ ag2, int nwork) {
  int group = (blockIdx.x * 256 + threadIdx.x) >> 4;
  int lane16 = threadIdx.x & 15;
  if (group >= nwork) return;
  int km1 = (group >= 2 * NODES) ? 2 : ((group >= NODES) ? 1 : 0);
  int d = group - km1 * NODES;
  __hip_bfloat16* ag = (km1 == 0) ? ag0 : ((km1 == 1) ? ag1 : ag2);
  int beg = rowptr[group], end = rowptr[group + 1];   // (end-beg)%4 == 0
  float a0 = 0.f, a1 = 0.f, a2 = 0.f, a3 = 0.f,
        a4 = 0.f, a5 = 0.f, a6 = 0.f, a7 = 0.f;
  for (int base = beg; base < end; base += 16) {
    int idxv = csr[base + lane16];            // slack-allocated
    int cnt = end - base; if (cnt > 16) cnt = 16;
    int q0 = __shfl(idxv, 0, 16);
    int q1 = __shfl(idxv, 1, 16);
    int q2 = __shfl(idxv, 2, 16);
    int q3 = __shfl(idxv, 3, 16);
    uint4 v0 = *(const uint4*)(src + (long)q0 * DIM + lane16 * 8);
    uint4 v1 = *(const uint4*)(src + (long)q1 * DIM + lane16 * 8);
    uint4 v2 = *(const uint4*)(src + (long)q2 * DIM + lane16 * 8);
    uint4 v3 = *(const uint4*)(src + (long)q3 * DIM + lane16 * 8);
    for (int j = 0; j < cnt; j += 4) {
      uint4 c0 = v0, c1 = v1, c2 = v2, c3 = v3;
      if (j + 4 < cnt) {                      // pipeline next 4 rows
        q0 = __shfl(idxv, j + 4, 16);
        q1 = __shfl(idxv, j + 5, 16);
        q2 = __shfl(idxv, j + 6, 16);
        q3 = __shfl(idxv, j + 7, 16);
        v0 = *(const uint4*)(src + (long)q0 * DIM + lane16 * 8);
        v1 = *(const uint4*)(src + (long)q1 * DIM + lane16 * 8);
        v2 = *(const uint4*)(src + (long)q2 * DIM + lane16 * 8);
        v3 = *(const uint4*)(src + (long)q3 * DIM + lane16 * 8);
      }
      a0 += __uint_as_float(c0.x << 16) + __uint_as_float(c1.x << 16)
          + __uint_as_float(c2.x << 16) + __uint_as_float(c3.x << 16);
      a1 += __uint_as_float(c0.x & 0xffff0000u) + __uint_as_float(c1.x & 0xffff0000u)
          + __uint_as_float(c2.x & 0xffff0000u) + __uint_as_float(c3.x & 0xffff0000u);
      a2 += __uint_as_float(c0.y << 16) + __uint_as_float(c1.y << 16)
          + __uint_as_float(c2.y << 16) + __uint_as_float(c3.y << 16);
      a3 += __uint_as_float(c0.y & 0xffff0000u) + __uint_as_float(c1.y & 0xffff0000u)
          + __uint_as_float(c2.y & 0xffff0000u) + __uint_as_float(c3.y & 0xffff0000u);
      a4 += __uint_as_float(c0.z << 16) + __uint_as_float(c1.z << 16)
          + __uint_as_float(c2.z << 16) + __uint_as_float(c3.z << 16);
      a5 += __uint_as_float(c0.z & 0xffff0000u) + __uint_as_float(c1.z & 0xffff0000u)
          + __uint_as_float(c2.z & 0xffff0000u) + __uint_as_float(c3.z & 0xffff0000u);
      a6 += __uint_as_float(c0.w << 16) + __uint_as_float(c1.w << 16)
          + __uint_as_float(c2.w << 16) + __uint_as_float(c3.w << 16);
      a7 += __uint_as_float(c0.w & 0xffff0000u) + __uint_as_float(c1.w & 0xffff0000u)
          + __uint_as_float(c2.w & 0xffff0000u) + __uint_as_float(c3.w & 0xffff0000u);
    }
  }
  union { __hip_bfloat16 h[8]; uint4 u; } pk;
  pk.h[0] = __float2bfloat16(a0); pk.h[1] = __float2bfloat16(a1);
  pk.h[2] = __float2bfloat16(a2); pk.h[3] = __float2bfloat16(a3);
  pk.h[4] = __float2bfloat16(a4); pk.h[5] = __float2bfloat16(a5);
  pk.h[6] = __float2bfloat16(a6); pk.h[7] = __float2bfloat16(a7);
  *(uint4*)(ag + (long)d * DIM + lane16 * 8) = pk.u;
}

// ---------------------------------------------------------------------------
// Layer GEMM (R12 version, proven): bf16 node state, A-frags direct from
// global, B staged in LDS.
__global__ __launch_bounds__(256, 4) void lgemm_kernel(
    const __hip_bfloat16* __restrict__ xbSelf,
    const __hip_bfloat16* __restrict__ ag0,
    const __hip_bfloat16* __restrict__ ag1,
    const __hip_bfloat16* __restrict__ ag2,
    const __hip_bfloat16* __restrict__ WT,
    const float* __restrict__ bs_t,
    const float* __restrict__ bk_t,
    const float* __restrict__ epsp,
    __hip_bfloat16* __restrict__ xnb,   // bf16 out (layers 0/1)
    float* __restrict__ xn,             // f32 out (final layer) or null
    int t) {
  __shared__ __hip_bfloat16 b_lds[128 * LDS_STRIDE];  // 34816 B

  int tid = threadIdx.x;
  long row0 = (long)blockIdx.x * 64;
  int wave = tid >> 6, lane = tid & 63;
  int l15 = lane & 15, q = lane >> 4;
  long arow = row0 + wave * 16 + l15;

  const __hip_bfloat16* Asrc[4] = {xbSelf, ag0, ag1, ag2};
  f32x4 out[8];

  for (int p = 0; p <= t + 1; ++p) {
    if (p > 0) __syncthreads();
    const __hip_bfloat16* Am = Asrc[p];
    uint4 af[4];
#pragma unroll
    for (int k0i = 0; k0i < 4; ++k0i)
      af[k0i] = *(const uint4*)(Am + arow * DIM + k0i * 32 + 8 * q);
    const __hip_bfloat16* W = (p == 0) ? (WT + (long)t * 16384)
                                       : (WT + (long)(3 + t * 3 + (p - 1)) * 16384);
    {
      const uint4* bq = (const uint4*)W;
#pragma unroll
      for (int i = 0; i < 8; ++i) {
        int idx = tid + 256 * i;
        int n = idx >> 4, k8 = idx & 15;
        uint4 v = bq[idx];
        *(uint4*)(b_lds + n * LDS_STRIDE + k8 * 8) = v;
      }
    }
    __syncthreads();

    f32x4 acc[8] = {};
#pragma unroll
    for (int k0i = 0; k0i < 4; ++k0i) {
      bf16x8 a = __builtin_bit_cast(bf16x8, af[k0i]);
#pragma unroll
      for (int j = 0; j < 8; ++j) {
        bf16x8 bfr = *(const bf16x8*)(b_lds + (16 * j + l15) * LDS_STRIDE + k0i * 32 + 8 * q);
        acc[j] = __builtin_amdgcn_mfma_f32_16x16x32_bf16(a, bfr, acc[j], 0, 0, 0);
      }
    }
    if (p == 0) {
      float sc = 1.0f + *epsp;
#pragma unroll
      for (int j = 0; j < 8; ++j) {
        float b = bs_t[16 * j + l15];
#pragma unroll
        for (int r = 0; r < 4; ++r) out[j][r] = sc * fmaxf(acc[j][r] + b, 0.f);
      }
    } else {
      const float* bb = bk_t + (p - 1) * 128;
#pragma unroll
      for (int j = 0; j < 8; ++j) {
        float b = bb[16 * j + l15];
#pragma unroll
        for (int r = 0; r < 4; ++r) out[j][r] += fmaxf(acc[j][r] + b, 0.f);
      }
    }
  }

  long rbase = row0 + wave * 16 + q * 4;
  bool fin = (xn != nullptr);
#pragma unroll
  for (int j = 0; j < 8; ++j) {
    int col = 16 * j + l15;
#pragma unroll
    for (int r = 0; r < 4; ++r) {
      long grow = rbase + r;
      if (grow < NODES) {
        float res = __bfloat162float(xbSelf[grow * DIM + col]);
        float v = res + fmaxf(out[j][r], 0.f);
        if (fin) xn[grow * DIM + col] = v;
        else     xnb[grow * DIM + col] = __float2bfloat16(v);
      }
    }
  }
}

// ---------------------------------------------------------------------------
extern "C" void kernel_launch(void* const* d_in, const int* in_sizes, int n_in,
                              void* d_out, int out_size, void* d_ws, size_t ws_size,
                              hipStream_t stream) {
  const float* x    = (const float*)d_in[0];
  const int*   ei   = (const int*)d_in[1];
  const int*   attr = (const int*)d_in[2];
  const float* Ws   = (const float*)d_in[3];
  const float* bs   = (const float*)d_in[4];
  const float* Wk   = (const float*)d_in[5];
  const float* bk   = (const float*)d_in[6];
  const float* eps  = (const float*)d_in[7];
  float* out = (float*)d_out;

  char* ws = (char*)d_ws;
  size_t off = 0;
  auto alloc = [&](size_t bytes) { char* p = ws + off; off += (bytes + 255) & ~(size_t)255; return p; };
  const size_t ROWB = (size_t)NROWP * DIM * 2;
  __hip_bfloat16* xb0  = (__hip_bfloat16*)alloc(ROWB);
  __hip_bfloat16* xb1  = (__hip_bfloat16*)alloc(ROWB);
  __hip_bfloat16* xb2  = (__hip_bfloat16*)alloc(ROWB);
  __hip_bfloat16* agA0 = (__hip_bfloat16*)alloc(ROWB);  // src xb0: layer0 k=1
  __hip_bfloat16* agA1 = (__hip_bfloat16*)alloc(ROWB);  // src xb0: layer1 k=2
  __hip_bfloat16* agA2 = (__hip_bfloat16*)alloc(ROWB);  // src xb0: layer2 k=3
  __hip_bfloat16* agB0 = (__hip_bfloat16*)alloc(ROWB);  // src xb1: layer1 k=1
  __hip_bfloat16* agB1 = (__hip_bfloat16*)alloc(ROWB);  // src xb1: layer2 k=2
  __hip_bfloat16* agC0 = (__hip_bfloat16*)alloc(ROWB);  // src xb2: layer2 k=1
  __hip_bfloat16* WT   = (__hip_bfloat16*)alloc(12 * 16384 * 2);
  int* cursor    = (int*)alloc((size_t)NB3 * 4);
  int* cur2      = (int*)alloc((size_t)NB3 * 4);
  int* rowptr    = (int*)alloc((size_t)(NB3 + 1) * 4 + 256);
  int* csr_src   = (int*)alloc((size_t)(EDGES + 4 * NB3 + 64) * 4);

  // 1: zero cursor (capture-legal async memset)
  hipMemsetAsync(cursor, 0, (size_t)NB3 * 4, stream);
  // 2: fused init + hist
  hipLaunchKernelGGL(init_hist_kernel, dim3(CGRID + 14 + EGRID), dim3(256), 0, stream,
                     x, Ws, Wk, xb0, xb1, xb2, WT, ei, attr, cursor);
  // 3: fused scan (rowptr + cur2 + csr pad)
  hipLaunchKernelGGL(scan_kernel, dim3(NBLKS), dim3(256), 0, stream,
                     cursor, rowptr, cur2, csr_src, NB3);
  // 4: single-pass fill
  hipLaunchKernelGGL(fill_kernel, dim3(EGRID), dim3(256), 0, stream,
                     ei, attr, cur2, csr_src, EDGES);

  auto glaunch = [&](int nwork, const __hip_bfloat16* src, __hip_bfloat16* a0,
                     __hip_bfloat16* a1, __hip_bfloat16* a2) {
    int blocks = (nwork * 16 + 255) / 256;
    hipLaunchKernelGGL(gather_kernel, dim3(blocks), dim3(256), 0, stream,
                       src, rowptr, csr_src, a0, a1, a2, nwork);
  };
  int ggrid = (NODES + 63) / 64;   // 782

  // 5: Gather A: all km1 from xb0.
  glaunch(3 * NODES, xb0, agA0, agA1, agA2);
  // 6: Layer 0.
  hipLaunchKernelGGL(lgemm_kernel, dim3(ggrid), dim3(256), 0, stream,
                     xb0, agA0, agA0, agA0, WT, bs + 0, bk + 0, eps + 0,
                     xb1, (float*)nullptr, 0);
  // 7: Gather B: km1 in {0,1} from xb1.
  glaunch(2 * NODES, xb1, agB0, agB1, agB1);
  // 8: Layer 1: k=1 -> agB0 (xb1), k=2 -> agA1 (xb0).
  hipLaunchKernelGGL(lgemm_kernel, dim3(ggrid), dim3(256), 0, stream,
                     xb1, agB0, agA1, agA1, WT, bs + 128, bk + 3 * 128, eps + 1,
                     xb2, (float*)nullptr, 1);
  // 9: Gather C: km1=0 from xb2.
  glaunch(NODES, xb2, agC0, agC0, agC0);
  // 10: Layer 2: k=1 -> agC0 (xb2), k=2 -> agB1 (xb1), k=3 -> agA2 (xb0).
  hipLaunchKernelGGL(lgemm_kernel, dim3(ggrid), dim3(256), 0, stream,
                     xb2, agC0, agB1, agA2, WT, bs + 256, bk + 6 * 128, eps + 2,
                     (__hip_bfloat16*)nullptr, out, 2);
}

// Round 19
// 318.692 us; speedup vs baseline: 1.2389x; 1.2389x over previous
//
#include <hip/hip_runtime.h>
#include <hip/hip_bf16.h>

// DRew-GIN: N=50000, E=800000, D=128, L=3, NU=1.
// R21 (315.8us): discrete front-end (km1-major) + identity worklist.
// R25 col-sliced gather: REJECTED (344.7) — L3-transaction bound, near floor.
// R27 gather (256,8): NULL — not occupancy-capped.
// R28 front-end fusion: 394.8 — scan fusion was O(n^2)-latency (scan_kernel
//   81.8us, occ 13%); memset+init_hist+1-pass-fill aggregate-neutral.
// R29: R28 with PROVEN two-kernel scan restored (scan_a + scanc over 587
//   blocksums); scanc also writes cur2 for single-pass fill. 11 dispatches.

#define NODES 50000
#define EDGES 800000
#define DIM   128
#define ND    ((long)NODES * DIM)
#define NB3   (3 * NODES)            // buckets: km1*NODES + d
#define NROWP 50048                  // row-padded tensors (tail tile slack)
#define NBLKS ((NB3 + 255) / 256)    // 587
#define EGRID ((EDGES + 255) / 256)  // 3125
#define CGRID ((int)(ND / 4 / 256))  // 6250 conversion blocks

typedef __attribute__((ext_vector_type(8))) short  bf16x8;
typedef __attribute__((ext_vector_type(4))) float  f32x4;

#define LDS_STRIDE 136   // bf16 elements; 272B rows

// ---------------------------------------------------------------------------
// Fused init + hist. cursor must be pre-zeroed (memset).
__global__ __launch_bounds__(256) void init_hist_kernel(
    const float* __restrict__ x, const float* __restrict__ Ws,
    const float* __restrict__ Wk, __hip_bfloat16* __restrict__ xb0,
    __hip_bfloat16* __restrict__ xb1, __hip_bfloat16* __restrict__ xb2,
    __hip_bfloat16* __restrict__ WT,
    const int* __restrict__ ei, const int* __restrict__ attr,
    int* __restrict__ cursor) {
  int b = blockIdx.x, tid = threadIdx.x;
  if (b < CGRID) {
    long i = (long)b * 256 + tid;          // < ND/4 exactly
    float4 v = ((const float4*)x)[i];
    union { __hip_bfloat16 h[4]; uint2 u; } pk;
    pk.h[0] = __float2bfloat16(v.x); pk.h[1] = __float2bfloat16(v.y);
    pk.h[2] = __float2bfloat16(v.z); pk.h[3] = __float2bfloat16(v.w);
    ((uint2*)xb0)[i] = pk.u;
  } else if (b < CGRID + 12) {
    int wb = b - CGRID;
    const float* src = (wb < 3) ? (Ws + (long)wb * 16384) : (Wk + (long)(wb - 3) * 16384);
    __hip_bfloat16* dst = WT + (long)wb * 16384;
    for (int idx = tid; idx < 16384; idx += 256) {
      int k = idx >> 7, n = idx & 127;
      dst[n * 128 + k] = __float2bfloat16(src[idx]);
    }
  } else if (b < CGRID + 14) {
    int g = (b - (CGRID + 12)) * 256 + tid;
    if (g < 3 * DIM) {
      int which = g >> 7, dcol = g & 127;
      __hip_bfloat16* xb = (which == 0) ? xb0 : ((which == 1) ? xb1 : xb2);
      xb[(long)NODES * DIM + dcol] = __float2bfloat16(0.f);
    }
  } else {
    int e = (b - (CGRID + 14)) * 256 + tid;
    if (e < EDGES)
      atomicAdd(&cursor[(attr[e] - 1) * NODES + ei[EDGES + e]], 1);
  }
}

// ---------------------------------------------------------------------------
// scan_a: per-block local exclusive scan of padded counts + blocksums.
__global__ __launch_bounds__(256) void scan_a_kernel(
    const int* __restrict__ counts, int* __restrict__ partial,
    int* __restrict__ blocksums, int n) {
  __shared__ int tmp[256];
  int gid = blockIdx.x * 256 + threadIdx.x;
  int v = (gid < n) ? ((counts[gid] + 3) & ~3) : 0;
  tmp[threadIdx.x] = v;
  __syncthreads();
  for (int off = 1; off < 256; off <<= 1) {
    int t = (threadIdx.x >= off) ? tmp[threadIdx.x - off] : 0;
    __syncthreads();
    tmp[threadIdx.x] += t;
    __syncthreads();
  }
  if (gid < n) partial[gid] = tmp[threadIdx.x] - v;
  if (threadIdx.x == 255) blocksums[blockIdx.x] = tmp[255];
}

// scanc: block prefix over 587 blocksums (cheap), writes rowptr + cur2 + pads.
__global__ __launch_bounds__(256) void scanc_kernel(
    int* __restrict__ rowptr, const int* __restrict__ cursor,
    int* __restrict__ cur2, const int* __restrict__ blocksums,
    int* __restrict__ csr, int n) {
  __shared__ int red[256];
  int tid = threadIdx.x;
  int partial = 0;
  for (int i = tid; i < blockIdx.x; i += 256) partial += blocksums[i];
  red[tid] = partial;
  __syncthreads();
  for (int off = 128; off > 0; off >>= 1) {
    if (tid < off) red[tid] += red[tid + off];
    __syncthreads();
  }
  int bsoff = red[0];
  int gid = blockIdx.x * 256 + tid;
  if (gid < n) {
    int cnt = cursor[gid];
    int pcnt = (cnt + 3) & ~3;
    int val = rowptr[gid] + bsoff;
    rowptr[gid] = val;
    cur2[gid] = val;
    for (int i = cnt; i < pcnt; ++i) csr[val + i] = NODES;
    if (gid == n - 1) rowptr[n] = val + pcnt;
  }
}

// Single-pass fill (scattered atomics on cur2; ~5 edges/bucket contention).
__global__ __launch_bounds__(256) void fill_kernel(
    const int* __restrict__ ei, const int* __restrict__ attr,
    int* __restrict__ cur2, int* __restrict__ csr_src, int E) {
  int e = blockIdx.x * 256 + threadIdx.x;
  if (e >= E) return;
  int pos = atomicAdd(&cur2[(attr[e] - 1) * NODES + ei[E + e]], 1);
  csr_src[pos] = ei[e];
}

// ---------------------------------------------------------------------------
// Gather (R21/R12 body, identity worklist, (256,6) proven config).
__global__ __launch_bounds__(256, 6) void gather_kernel(
    const __hip_bfloat16* __restrict__ src,
    const int* __restrict__ rowptr, const int* __restrict__ csr,
    __hip_bfloat16* __restrict__ ag0, __hip_bfloat16* __restrict__ ag1,
    __hip_bfloat16* __restrict__ ag2, int nwork) {
  int group = (blockIdx.x * 256 + threadIdx.x) >> 4;
  int lane16 = threadIdx.x & 15;
  if (group >= nwork) return;
  int km1 = (group >= 2 * NODES) ? 2 : ((group >= NODES) ? 1 : 0);
  int d = group - km1 * NODES;
  __hip_bfloat16* ag = (km1 == 0) ? ag0 : ((km1 == 1) ? ag1 : ag2);
  int beg = rowptr[group], end = rowptr[group + 1];   // (end-beg)%4 == 0
  float a0 = 0.f, a1 = 0.f, a2 = 0.f, a3 = 0.f,
        a4 = 0.f, a5 = 0.f, a6 = 0.f, a7 = 0.f;
  for (int base = beg; base < end; base += 16) {
    int idxv = csr[base + lane16];            // slack-allocated
    int cnt = end - base; if (cnt > 16) cnt = 16;
    int q0 = __shfl(idxv, 0, 16);
    int q1 = __shfl(idxv, 1, 16);
    int q2 = __shfl(idxv, 2, 16);
    int q3 = __shfl(idxv, 3, 16);
    uint4 v0 = *(const uint4*)(src + (long)q0 * DIM + lane16 * 8);
    uint4 v1 = *(const uint4*)(src + (long)q1 * DIM + lane16 * 8);
    uint4 v2 = *(const uint4*)(src + (long)q2 * DIM + lane16 * 8);
    uint4 v3 = *(const uint4*)(src + (long)q3 * DIM + lane16 * 8);
    for (int j = 0; j < cnt; j += 4) {
      uint4 c0 = v0, c1 = v1, c2 = v2, c3 = v3;
      if (j + 4 < cnt) {                      // pipeline next 4 rows
        q0 = __shfl(idxv, j + 4, 16);
        q1 = __shfl(idxv, j + 5, 16);
        q2 = __shfl(idxv, j + 6, 16);
        q3 = __shfl(idxv, j + 7, 16);
        v0 = *(const uint4*)(src + (long)q0 * DIM + lane16 * 8);
        v1 = *(const uint4*)(src + (long)q1 * DIM + lane16 * 8);
        v2 = *(const uint4*)(src + (long)q2 * DIM + lane16 * 8);
        v3 = *(const uint4*)(src + (long)q3 * DIM + lane16 * 8);
      }
      a0 += __uint_as_float(c0.x << 16) + __uint_as_float(c1.x << 16)
          + __uint_as_float(c2.x << 16) + __uint_as_float(c3.x << 16);
      a1 += __uint_as_float(c0.x & 0xffff0000u) + __uint_as_float(c1.x & 0xffff0000u)
          + __uint_as_float(c2.x & 0xffff0000u) + __uint_as_float(c3.x & 0xffff0000u);
      a2 += __uint_as_float(c0.y << 16) + __uint_as_float(c1.y << 16)
          + __uint_as_float(c2.y << 16) + __uint_as_float(c3.y << 16);
      a3 += __uint_as_float(c0.y & 0xffff0000u) + __uint_as_float(c1.y & 0xffff0000u)
          + __uint_as_float(c2.y & 0xffff0000u) + __uint_as_float(c3.y & 0xffff0000u);
      a4 += __uint_as_float(c0.z << 16) + __uint_as_float(c1.z << 16)
          + __uint_as_float(c2.z << 16) + __uint_as_float(c3.z << 16);
      a5 += __uint_as_float(c0.z & 0xffff0000u) + __uint_as_float(c1.z & 0xffff0000u)
          + __uint_as_float(c2.z & 0xffff0000u) + __uint_as_float(c3.z & 0xffff0000u);
      a6 += __uint_as_float(c0.w << 16) + __uint_as_float(c1.w << 16)
          + __uint_as_float(c2.w << 16) + __uint_as_float(c3.w << 16);
      a7 += __uint_as_float(c0.w & 0xffff0000u) + __uint_as_float(c1.w & 0xffff0000u)
          + __uint_as_float(c2.w & 0xffff0000u) + __uint_as_float(c3.w & 0xffff0000u);
    }
  }
  union { __hip_bfloat16 h[8]; uint4 u; } pk;
  pk.h[0] = __float2bfloat16(a0); pk.h[1] = __float2bfloat16(a1);
  pk.h[2] = __float2bfloat16(a2); pk.h[3] = __float2bfloat16(a3);
  pk.h[4] = __float2bfloat16(a4); pk.h[5] = __float2bfloat16(a5);
  pk.h[6] = __float2bfloat16(a6); pk.h[7] = __float2bfloat16(a7);
  *(uint4*)(ag + (long)d * DIM + lane16 * 8) = pk.u;
}

// ---------------------------------------------------------------------------
// Layer GEMM (R12 version, proven): bf16 node state, A-frags direct from
// global, B staged in LDS.
__global__ __launch_bounds__(256, 4) void lgemm_kernel(
    const __hip_bfloat16* __restrict__ xbSelf,
    const __hip_bfloat16* __restrict__ ag0,
    const __hip_bfloat16* __restrict__ ag1,
    const __hip_bfloat16* __restrict__ ag2,
    const __hip_bfloat16* __restrict__ WT,
    const float* __restrict__ bs_t,
    const float* __restrict__ bk_t,
    const float* __restrict__ epsp,
    __hip_bfloat16* __restrict__ xnb,   // bf16 out (layers 0/1)
    float* __restrict__ xn,             // f32 out (final layer) or null
    int t) {
  __shared__ __hip_bfloat16 b_lds[128 * LDS_STRIDE];  // 34816 B

  int tid = threadIdx.x;
  long row0 = (long)blockIdx.x * 64;
  int wave = tid >> 6, lane = tid & 63;
  int l15 = lane & 15, q = lane >> 4;
  long arow = row0 + wave * 16 + l15;

  const __hip_bfloat16* Asrc[4] = {xbSelf, ag0, ag1, ag2};
  f32x4 out[8];

  for (int p = 0; p <= t + 1; ++p) {
    if (p > 0) __syncthreads();
    const __hip_bfloat16* Am = Asrc[p];
    uint4 af[4];
#pragma unroll
    for (int k0i = 0; k0i < 4; ++k0i)
      af[k0i] = *(const uint4*)(Am + arow * DIM + k0i * 32 + 8 * q);
    const __hip_bfloat16* W = (p == 0) ? (WT + (long)t * 16384)
                                       : (WT + (long)(3 + t * 3 + (p - 1)) * 16384);
    {
      const uint4* bq = (const uint4*)W;
#pragma unroll
      for (int i = 0; i < 8; ++i) {
        int idx = tid + 256 * i;
        int n = idx >> 4, k8 = idx & 15;
        uint4 v = bq[idx];
        *(uint4*)(b_lds + n * LDS_STRIDE + k8 * 8) = v;
      }
    }
    __syncthreads();

    f32x4 acc[8] = {};
#pragma unroll
    for (int k0i = 0; k0i < 4; ++k0i) {
      bf16x8 a = __builtin_bit_cast(bf16x8, af[k0i]);
#pragma unroll
      for (int j = 0; j < 8; ++j) {
        bf16x8 bfr = *(const bf16x8*)(b_lds + (16 * j + l15) * LDS_STRIDE + k0i * 32 + 8 * q);
        acc[j] = __builtin_amdgcn_mfma_f32_16x16x32_bf16(a, bfr, acc[j], 0, 0, 0);
      }
    }
    if (p == 0) {
      float sc = 1.0f + *epsp;
#pragma unroll
      for (int j = 0; j < 8; ++j) {
        float b = bs_t[16 * j + l15];
#pragma unroll
        for (int r = 0; r < 4; ++r) out[j][r] = sc * fmaxf(acc[j][r] + b, 0.f);
      }
    } else {
      const float* bb = bk_t + (p - 1) * 128;
#pragma unroll
      for (int j = 0; j < 8; ++j) {
        float b = bb[16 * j + l15];
#pragma unroll
        for (int r = 0; r < 4; ++r) out[j][r] += fmaxf(acc[j][r] + b, 0.f);
      }
    }
  }

  long rbase = row0 + wave * 16 + q * 4;
  bool fin = (xn != nullptr);
#pragma unroll
  for (int j = 0; j < 8; ++j) {
    int col = 16 * j + l15;
#pragma unroll
    for (int r = 0; r < 4; ++r) {
      long grow = rbase + r;
      if (grow < NODES) {
        float res = __bfloat162float(xbSelf[grow * DIM + col]);
        float v = res + fmaxf(out[j][r], 0.f);
        if (fin) xn[grow * DIM + col] = v;
        else     xnb[grow * DIM + col] = __float2bfloat16(v);
      }
    }
  }
}

// ---------------------------------------------------------------------------
extern "C" void kernel_launch(void* const* d_in, const int* in_sizes, int n_in,
                              void* d_out, int out_size, void* d_ws, size_t ws_size,
                              hipStream_t stream) {
  const float* x    = (const float*)d_in[0];
  const int*   ei   = (const int*)d_in[1];
  const int*   attr = (const int*)d_in[2];
  const float* Ws   = (const float*)d_in[3];
  const float* bs   = (const float*)d_in[4];
  const float* Wk   = (const float*)d_in[5];
  const float* bk   = (const float*)d_in[6];
  const float* eps  = (const float*)d_in[7];
  float* out = (float*)d_out;

  char* ws = (char*)d_ws;
  size_t off = 0;
  auto alloc = [&](size_t bytes) { char* p = ws + off; off += (bytes + 255) & ~(size_t)255; return p; };
  const size_t ROWB = (size_t)NROWP * DIM * 2;
  __hip_bfloat16* xb0  = (__hip_bfloat16*)alloc(ROWB);
  __hip_bfloat16* xb1  = (__hip_bfloat16*)alloc(ROWB);
  __hip_bfloat16* xb2  = (__hip_bfloat16*)alloc(ROWB);
  __hip_bfloat16* agA0 = (__hip_bfloat16*)alloc(ROWB);  // src xb0: layer0 k=1
  __hip_bfloat16* agA1 = (__hip_bfloat16*)alloc(ROWB);  // src xb0: layer1 k=2
  __hip_bfloat16* agA2 = (__hip_bfloat16*)alloc(ROWB);  // src xb0: layer2 k=3
  __hip_bfloat16* agB0 = (__hip_bfloat16*)alloc(ROWB);  // src xb1: layer1 k=1
  __hip_bfloat16* agB1 = (__hip_bfloat16*)alloc(ROWB);  // src xb1: layer2 k=2
  __hip_bfloat16* agC0 = (__hip_bfloat16*)alloc(ROWB);  // src xb2: layer2 k=1
  __hip_bfloat16* WT   = (__hip_bfloat16*)alloc(12 * 16384 * 2);
  int* cursor    = (int*)alloc((size_t)NB3 * 4);
  int* cur2      = (int*)alloc((size_t)NB3 * 4);
  int* rowptr    = (int*)alloc((size_t)(NB3 + 1) * 4 + 256);
  int* blocksums = (int*)alloc(1024 * 4);
  int* csr_src   = (int*)alloc((size_t)(EDGES + 4 * NB3 + 64) * 4);

  // 1: zero cursor (capture-legal async memset)
  hipMemsetAsync(cursor, 0, (size_t)NB3 * 4, stream);
  // 2: fused init + hist
  hipLaunchKernelGGL(init_hist_kernel, dim3(CGRID + 14 + EGRID), dim3(256), 0, stream,
                     x, Ws, Wk, xb0, xb1, xb2, WT, ei, attr, cursor);
  // 3: scan_a (proven)
  hipLaunchKernelGGL(scan_a_kernel, dim3(NBLKS), dim3(256), 0, stream,
                     cursor, rowptr, blocksums, NB3);
  // 4: scanc (proven; also writes cur2)
  hipLaunchKernelGGL(scanc_kernel, dim3(NBLKS), dim3(256), 0, stream,
                     rowptr, cursor, cur2, blocksums, csr_src, NB3);
  // 5: single-pass fill
  hipLaunchKernelGGL(fill_kernel, dim3(EGRID), dim3(256), 0, stream,
                     ei, attr, cur2, csr_src, EDGES);

  auto glaunch = [&](int nwork, const __hip_bfloat16* src, __hip_bfloat16* a0,
                     __hip_bfloat16* a1, __hip_bfloat16* a2) {
    int blocks = (nwork * 16 + 255) / 256;
    hipLaunchKernelGGL(gather_kernel, dim3(blocks), dim3(256), 0, stream,
                       src, rowptr, csr_src, a0, a1, a2, nwork);
  };
  int ggrid = (NODES + 63) / 64;   // 782

  // 6: Gather A: all km1 from xb0.
  glaunch(3 * NODES, xb0, agA0, agA1, agA2);
  // 7: Layer 0.
  hipLaunchKernelGGL(lgemm_kernel, dim3(ggrid), dim3(256), 0, stream,
                     xb0, agA0, agA0, agA0, WT, bs + 0, bk + 0, eps + 0,
                     xb1, (float*)nullptr, 0);
  // 8: Gather B: km1 in {0,1} from xb1.
  glaunch(2 * NODES, xb1, agB0, agB1, agB1);
  // 9: Layer 1: k=1 -> agB0 (xb1), k=2 -> agA1 (xb0).
  hipLaunchKernelGGL(lgemm_kernel, dim3(ggrid), dim3(256), 0, stream,
                     xb1, agB0, agA1, agA1, WT, bs + 128, bk + 3 * 128, eps + 1,
                     xb2, (float*)nullptr, 1);
  // 10: Gather C: km1=0 from xb2.
  glaunch(NODES, xb2, agC0, agC0, agC0);
  // 11: Layer 2: k=1 -> agC0 (xb2), k=2 -> agB1 (xb1), k=3 -> agA2 (xb0).
  hipLaunchKernelGGL(lgemm_kernel, dim3(ggrid), dim3(256), 0, stream,
                     xb2, agC0, agB1, agA2, WT, bs + 256, bk + 6 * 128, eps + 2,
                     (__hip_bfloat16*)nullptr, out, 2);
}

// Round 23
// 303.263 us; speedup vs baseline: 1.3020x; 1.0509x over previous
//
#include <hip/hip_runtime.h>
#include <hip/hip_bf16.h>

// DRew-GIN: N=50000, E=800000, D=128, L=3, NU=1.
// R21 (315.8us, reference): discrete front-end (km1-major) + identity
//   worklist + R12 gather/lgemm bodies. 11 launches.
// R25 col-sliced gather: REJECTED. R27 (256,8): NULL. R28/R29 front-end
//   restructure: net-neutral (scan fusion O(n^2) fixed, rest ~0).
// R29 counter find: init_hist 53-63us @ VALU 0.9%, HBM 11% — the 12-block
//   weight transpose (64 iters of 256B-stride scatter-STORES on 12 CUs) is
//   the latency pole; same code lives in R21's init.
// R30: R21 EXACTLY + weight transpose spread over 768 blocks, 1 elem/thread,
//   coalesced writes + strided reads (scatter loads hide; scatter stores
//   stall). Single change.
// R31/R32/R33: resubmit unchanged — R30 bench infra-failed (GPU timeouts).

#define NODES 50000
#define EDGES 800000
#define DIM   128
#define ND    ((long)NODES * DIM)
#define NB3   (3 * NODES)            // buckets: km1*NODES + d
#define NPART 4
#define PSIZE (NODES / NPART)        // 12500
#define NROWP 50048                  // row-padded tensors (tail tile slack)
#define NBLKS ((NB3 + 255) / 256)    // 587

typedef __attribute__((ext_vector_type(8))) short  bf16x8;
typedef __attribute__((ext_vector_type(4))) float  f32x4;

#define LDS_STRIDE 136   // bf16 elements; 272B rows

// ---------------------------------------------------------------------------
// init: x->bf16 shadow, PARALLEL weight transpose (768 blocks, coalesced
// writes), cursor zero, dummy-row zero.
__global__ __launch_bounds__(256) void init_kernel(
    const float* __restrict__ x, const float* __restrict__ Ws,
    const float* __restrict__ Wk, __hip_bfloat16* __restrict__ xb0,
    __hip_bfloat16* __restrict__ xb1, __hip_bfloat16* __restrict__ xb2,
    __hip_bfloat16* __restrict__ WT, int* __restrict__ cursor) {
  int b = blockIdx.x, tid = threadIdx.x;
  long i = (long)b * 256 + tid;
  if (i < ND / 4) {
    float4 v = ((const float4*)x)[i];
    union { __hip_bfloat16 h[4]; uint2 u; } pk;
    pk.h[0] = __float2bfloat16(v.x); pk.h[1] = __float2bfloat16(v.y);
    pk.h[2] = __float2bfloat16(v.z); pk.h[3] = __float2bfloat16(v.w);
    ((uint2*)xb0)[i] = pk.u;
  }
  if (b >= 12 && b < 780) {
    // Weight transpose: out_idx consecutive -> coalesced WT writes; reads
    // strided (src[k*128+n], 512B apart per lane) — load-queue hides.
    int widx = (b - 12) * 256 + tid;       // 0..196607
    int wb = widx >> 14;                    // matrix 0..11
    int r  = widx & 16383;                  // transposed out index n*128+k
    int n = r >> 7, k = r & 127;
    const float* src = (wb < 3) ? (Ws + (long)wb * 16384) : (Wk + (long)(wb - 3) * 16384);
    WT[(long)wb * 16384 + r] = __float2bfloat16(src[k * 128 + n]);
  }
  if (b >= 780 && b < 780 + NBLKS) {
    int g = (b - 780) * 256 + tid;
    if (g < NB3) cursor[g] = 0;
  }
  if (b == 1400 && tid < DIM) {
    xb0[(long)NODES * DIM + tid] = __float2bfloat16(0.f);
    xb1[(long)NODES * DIM + tid] = __float2bfloat16(0.f);
    xb2[(long)NODES * DIM + tid] = __float2bfloat16(0.f);
  }
}

// ---------------------------------------------------------------------------
// CSR build (pad-to-4), km1-major bucket ids: bid = (attr-1)*NODES + dst.
__global__ __launch_bounds__(256) void hist_kernel(
    const int* __restrict__ ei, const int* __restrict__ attr,
    int* __restrict__ counts, int E) {
  int e = blockIdx.x * 256 + threadIdx.x;
  if (e >= E) return;
  atomicAdd(&counts[(attr[e] - 1) * NODES + ei[E + e]], 1);
}

__global__ __launch_bounds__(256) void scan_a_kernel(
    const int* __restrict__ counts, int* __restrict__ partial,
    int* __restrict__ blocksums, int n) {
  __shared__ int tmp[256];
  int gid = blockIdx.x * 256 + threadIdx.x;
  int v = (gid < n) ? ((counts[gid] + 3) & ~3) : 0;
  tmp[threadIdx.x] = v;
  __syncthreads();
  for (int off = 1; off < 256; off <<= 1) {
    int t = (threadIdx.x >= off) ? tmp[threadIdx.x - off] : 0;
    __syncthreads();
    tmp[threadIdx.x] += t;
    __syncthreads();
  }
  if (gid < n) partial[gid] = tmp[threadIdx.x] - v;
  if (threadIdx.x == 255) blocksums[blockIdx.x] = tmp[255];
}

// scan_c: computes its own exclusive blocksum prefix, writes rowptr/cursor,
// fills pad-slack csr entries with dummy node id. (Proven R13/R17/R21.)
__global__ __launch_bounds__(256) void scanc_kernel(
    int* __restrict__ rowptr, int* __restrict__ cursor,
    const int* __restrict__ blocksums, int* __restrict__ csr, int n) {
  __shared__ int red[256];
  int tid = threadIdx.x;
  int partial = 0;
  for (int i = tid; i < blockIdx.x; i += 256) partial += blocksums[i];
  red[tid] = partial;
  __syncthreads();
  for (int off = 128; off > 0; off >>= 1) {
    if (tid < off) red[tid] += red[tid + off];
    __syncthreads();
  }
  int bsoff = red[0];
  int gid = blockIdx.x * 256 + tid;
  if (gid < n) {
    int cnt = cursor[gid];
    int pcnt = (cnt + 3) & ~3;
    int val = rowptr[gid] + bsoff;
    rowptr[gid] = val;
    cursor[gid] = val;
    for (int i = cnt; i < pcnt; ++i) csr[val + i] = NODES;
    if (gid == n - 1) rowptr[n] = val + pcnt;
  }
}

__global__ __launch_bounds__(256) void fill_kernel(
    const int* __restrict__ ei, const int* __restrict__ attr,
    int* __restrict__ cursor, int* __restrict__ csr_src, int E) {
  int p = blockIdx.x & (NPART - 1);
  int chunk = blockIdx.x >> 2;
  int e = chunk * 256 + threadIdx.x;
  if (e >= E) return;
  int d = ei[E + e];
  int lo = p * PSIZE;
  if (d < lo || d >= lo + PSIZE) return;
  int pos = atomicAdd(&cursor[(attr[e] - 1) * NODES + d], 1);
  csr_src[pos] = ei[e];
}

// ---------------------------------------------------------------------------
// Gather (R21/R12 body, identity worklist, (256,6) proven config).
__global__ __launch_bounds__(256, 6) void gather_kernel(
    const __hip_bfloat16* __restrict__ src,
    const int* __restrict__ rowptr, const int* __restrict__ csr,
    __hip_bfloat16* __restrict__ ag0, __hip_bfloat16* __restrict__ ag1,
    __hip_bfloat16* __restrict__ ag2, int nwork) {
  int group = (blockIdx.x * 256 + threadIdx.x) >> 4;
  int lane16 = threadIdx.x & 15;
  if (group >= nwork) return;
  int km1 = (group >= 2 * NODES) ? 2 : ((group >= NODES) ? 1 : 0);
  int d = group - km1 * NODES;
  __hip_bfloat16* ag = (km1 == 0) ? ag0 : ((km1 == 1) ? ag1 : ag2);
  int beg = rowptr[group], end = rowptr[group + 1];   // (end-beg)%4 == 0
  float a0 = 0.f, a1 = 0.f, a2 = 0.f, a3 = 0.f,
        a4 = 0.f, a5 = 0.f, a6 = 0.f, a7 = 0.f;
  for (int base = beg; base < end; base += 16) {
    int idxv = csr[base + lane16];            // slack-allocated
    int cnt = end - base; if (cnt > 16) cnt = 16;
    int q0 = __shfl(idxv, 0, 16);
    int q1 = __shfl(idxv, 1, 16);
    int q2 = __shfl(idxv, 2, 16);
    int q3 = __shfl(idxv, 3, 16);
    uint4 v0 = *(const uint4*)(src + (long)q0 * DIM + lane16 * 8);
    uint4 v1 = *(const uint4*)(src + (long)q1 * DIM + lane16 * 8);
    uint4 v2 = *(const uint4*)(src + (long)q2 * DIM + lane16 * 8);
    uint4 v3 = *(const uint4*)(src + (long)q3 * DIM + lane16 * 8);
    for (int j = 0; j < cnt; j += 4) {
      uint4 c0 = v0, c1 = v1, c2 = v2, c3 = v3;
      if (j + 4 < cnt) {                      // pipeline next 4 rows
        q0 = __shfl(idxv, j + 4, 16);
        q1 = __shfl(idxv, j + 5, 16);
        q2 = __shfl(idxv, j + 6, 16);
        q3 = __shfl(idxv, j + 7, 16);
        v0 = *(const uint4*)(src + (long)q0 * DIM + lane16 * 8);
        v1 = *(const uint4*)(src + (long)q1 * DIM + lane16 * 8);
        v2 = *(const uint4*)(src + (long)q2 * DIM + lane16 * 8);
        v3 = *(const uint4*)(src + (long)q3 * DIM + lane16 * 8);
      }
      a0 += __uint_as_float(c0.x << 16) + __uint_as_float(c1.x << 16)
          + __uint_as_float(c2.x << 16) + __uint_as_float(c3.x << 16);
      a1 += __uint_as_float(c0.x & 0xffff0000u) + __uint_as_float(c1.x & 0xffff0000u)
          + __uint_as_float(c2.x & 0xffff0000u) + __uint_as_float(c3.x & 0xffff0000u);
      a2 += __uint_as_float(c0.y << 16) + __uint_as_float(c1.y << 16)
          + __uint_as_float(c2.y << 16) + __uint_as_float(c3.y << 16);
      a3 += __uint_as_float(c0.y & 0xffff0000u) + __uint_as_float(c1.y & 0xffff0000u)
          + __uint_as_float(c2.y & 0xffff0000u) + __uint_as_float(c3.y & 0xffff0000u);
      a4 += __uint_as_float(c0.z << 16) + __uint_as_float(c1.z << 16)
          + __uint_as_float(c2.z << 16) + __uint_as_float(c3.z << 16);
      a5 += __uint_as_float(c0.z & 0xffff0000u) + __uint_as_float(c1.z & 0xffff0000u)
          + __uint_as_float(c2.z & 0xffff0000u) + __uint_as_float(c3.z & 0xffff0000u);
      a6 += __uint_as_float(c0.w << 16) + __uint_as_float(c1.w << 16)
          + __uint_as_float(c2.w << 16) + __uint_as_float(c3.w << 16);
      a7 += __uint_as_float(c0.w & 0xffff0000u) + __uint_as_float(c1.w & 0xffff0000u)
          + __uint_as_float(c2.w & 0xffff0000u) + __uint_as_float(c3.w & 0xffff0000u);
    }
  }
  union { __hip_bfloat16 h[8]; uint4 u; } pk;
  pk.h[0] = __float2bfloat16(a0); pk.h[1] = __float2bfloat16(a1);
  pk.h[2] = __float2bfloat16(a2); pk.h[3] = __float2bfloat16(a3);
  pk.h[4] = __float2bfloat16(a4); pk.h[5] = __float2bfloat16(a5);
  pk.h[6] = __float2bfloat16(a6); pk.h[7] = __float2bfloat16(a7);
  *(uint4*)(ag + (long)d * DIM + lane16 * 8) = pk.u;
}

// ---------------------------------------------------------------------------
// Layer GEMM (R12 version, proven): bf16 node state, A-frags direct from
// global, B staged in LDS.
__global__ __launch_bounds__(256, 4) void lgemm_kernel(
    const __hip_bfloat16* __restrict__ xbSelf,
    const __hip_bfloat16* __restrict__ ag0,
    const __hip_bfloat16* __restrict__ ag1,
    const __hip_bfloat16* __restrict__ ag2,
    const __hip_bfloat16* __restrict__ WT,
    const float* __restrict__ bs_t,
    const float* __restrict__ bk_t,
    const float* __restrict__ epsp,
    __hip_bfloat16* __restrict__ xnb,   // bf16 out (layers 0/1)
    float* __restrict__ xn,             // f32 out (final layer) or null
    int t) {
  __shared__ __hip_bfloat16 b_lds[128 * LDS_STRIDE];  // 34816 B

  int tid = threadIdx.x;
  long row0 = (long)blockIdx.x * 64;
  int wave = tid >> 6, lane = tid & 63;
  int l15 = lane & 15, q = lane >> 4;
  long arow = row0 + wave * 16 + l15;

  const __hip_bfloat16* Asrc[4] = {xbSelf, ag0, ag1, ag2};
  f32x4 out[8];

  for (int p = 0; p <= t + 1; ++p) {
    if (p > 0) __syncthreads();
    const __hip_bfloat16* Am = Asrc[p];
    uint4 af[4];
#pragma unroll
    for (int k0i = 0; k0i < 4; ++k0i)
      af[k0i] = *(const uint4*)(Am + arow * DIM + k0i * 32 + 8 * q);
    const __hip_bfloat16* W = (p == 0) ? (WT + (long)t * 16384)
                                       : (WT + (long)(3 + t * 3 + (p - 1)) * 16384);
    {
      const uint4* bq = (const uint4*)W;
#pragma unroll
      for (int i = 0; i < 8; ++i) {
        int idx = tid + 256 * i;
        int n = idx >> 4, k8 = idx & 15;
        uint4 v = bq[idx];
        *(uint4*)(b_lds + n * LDS_STRIDE + k8 * 8) = v;
      }
    }
    __syncthreads();

    f32x4 acc[8] = {};
#pragma unroll
    for (int k0i = 0; k0i < 4; ++k0i) {
      bf16x8 a = __builtin_bit_cast(bf16x8, af[k0i]);
#pragma unroll
      for (int j = 0; j < 8; ++j) {
        bf16x8 bfr = *(const bf16x8*)(b_lds + (16 * j + l15) * LDS_STRIDE + k0i * 32 + 8 * q);
        acc[j] = __builtin_amdgcn_mfma_f32_16x16x32_bf16(a, bfr, acc[j], 0, 0, 0);
      }
    }
    if (p == 0) {
      float sc = 1.0f + *epsp;
#pragma unroll
      for (int j = 0; j < 8; ++j) {
        float b = bs_t[16 * j + l15];
#pragma unroll
        for (int r = 0; r < 4; ++r) out[j][r] = sc * fmaxf(acc[j][r] + b, 0.f);
      }
    } else {
      const float* bb = bk_t + (p - 1) * 128;
#pragma unroll
      for (int j = 0; j < 8; ++j) {
        float b = bb[16 * j + l15];
#pragma unroll
        for (int r = 0; r < 4; ++r) out[j][r] += fmaxf(acc[j][r] + b, 0.f);
      }
    }
  }

  long rbase = row0 + wave * 16 + q * 4;
  bool fin = (xn != nullptr);
#pragma unroll
  for (int j = 0; j < 8; ++j) {
    int col = 16 * j + l15;
#pragma unroll
    for (int r = 0; r < 4; ++r) {
      long grow = rbase + r;
      if (grow < NODES) {
        float res = __bfloat162float(xbSelf[grow * DIM + col]);
        float v = res + fmaxf(out[j][r], 0.f);
        if (fin) xn[grow * DIM + col] = v;
        else     xnb[grow * DIM + col] = __float2bfloat16(v);
      }
    }
  }
}

// ---------------------------------------------------------------------------
extern "C" void kernel_launch(void* const* d_in, const int* in_sizes, int n_in,
                              void* d_out, int out_size, void* d_ws, size_t ws_size,
                              hipStream_t stream) {
  const float* x    = (const float*)d_in[0];
  const int*   ei   = (const int*)d_in[1];
  const int*   attr = (const int*)d_in[2];
  const float* Ws   = (const float*)d_in[3];
  const float* bs   = (const float*)d_in[4];
  const float* Wk   = (const float*)d_in[5];
  const float* bk   = (const float*)d_in[6];
  const float* eps  = (const float*)d_in[7];
  float* out = (float*)d_out;

  char* ws = (char*)d_ws;
  size_t off = 0;
  auto alloc = [&](size_t bytes) { char* p = ws + off; off += (bytes + 255) & ~(size_t)255; return p; };
  const size_t ROWB = (size_t)NROWP * DIM * 2;
  __hip_bfloat16* xb0  = (__hip_bfloat16*)alloc(ROWB);
  __hip_bfloat16* xb1  = (__hip_bfloat16*)alloc(ROWB);
  __hip_bfloat16* xb2  = (__hip_bfloat16*)alloc(ROWB);
  __hip_bfloat16* agA0 = (__hip_bfloat16*)alloc(ROWB);  // src xb0: layer0 k=1
  __hip_bfloat16* agA1 = (__hip_bfloat16*)alloc(ROWB);  // src xb0: layer1 k=2
  __hip_bfloat16* agA2 = (__hip_bfloat16*)alloc(ROWB);  // src xb0: layer2 k=3
  __hip_bfloat16* agB0 = (__hip_bfloat16*)alloc(ROWB);  // src xb1: layer1 k=1
  __hip_bfloat16* agB1 = (__hip_bfloat16*)alloc(ROWB);  // src xb1: layer2 k=2
  __hip_bfloat16* agC0 = (__hip_bfloat16*)alloc(ROWB);  // src xb2: layer2 k=1
  __hip_bfloat16* WT   = (__hip_bfloat16*)alloc(12 * 16384 * 2);
  int* cursor    = (int*)alloc((size_t)NB3 * 4);
  int* rowptr    = (int*)alloc((size_t)(NB3 + 1) * 4 + 256);
  int* blocksums = (int*)alloc(1024 * 4);
  int* csr_src   = (int*)alloc((size_t)(EDGES + 4 * NB3 + 64) * 4);

  int egrid  = (EDGES + 255) / 256;        // 3125
  int igrid  = (int)(ND / 4 / 256);        // 6250

  hipLaunchKernelGGL(init_kernel, dim3(igrid), dim3(256), 0, stream,
                     x, Ws, Wk, xb0, xb1, xb2, WT, cursor);
  hipLaunchKernelGGL(hist_kernel, dim3(egrid), dim3(256), 0, stream, ei, attr, cursor, EDGES);
  hipLaunchKernelGGL(scan_a_kernel, dim3(NBLKS), dim3(256), 0, stream, cursor, rowptr, blocksums, NB3);
  hipLaunchKernelGGL(scanc_kernel, dim3(NBLKS), dim3(256), 0, stream,
                     rowptr, cursor, blocksums, csr_src, NB3);
  hipLaunchKernelGGL(fill_kernel, dim3(egrid * NPART), dim3(256), 0, stream, ei, attr, cursor, csr_src, EDGES);

  auto glaunch = [&](int nwork, const __hip_bfloat16* src, __hip_bfloat16* a0,
                     __hip_bfloat16* a1, __hip_bfloat16* a2) {
    int blocks = (nwork * 16 + 255) / 256;
    hipLaunchKernelGGL(gather_kernel, dim3(blocks), dim3(256), 0, stream,
                       src, rowptr, csr_src, a0, a1, a2, nwork);
  };
  int ggrid = (NODES + 63) / 64;   // 782

  // Gather A: all km1 from xb0.
  glaunch(3 * NODES, xb0, agA0, agA1, agA2);
  // Layer 0.
  hipLaunchKernelGGL(lgemm_kernel, dim3(ggrid), dim3(256), 0, stream,
                     xb0, agA0, agA0, agA0, WT, bs + 0, bk + 0, eps + 0,
                     xb1, (float*)nullptr, 0);
  // Gather B: km1 in {0,1} from xb1.
  glaunch(2 * NODES, xb1, agB0, agB1, agB1);
  // Layer 1: k=1 -> agB0 (xb1), k=2 -> agA1 (xb0).
  hipLaunchKernelGGL(lgemm_kernel, dim3(ggrid), dim3(256), 0, stream,
                     xb1, agB0, agA1, agA1, WT, bs + 128, bk + 3 * 128, eps + 1,
                     xb2, (float*)nullptr, 1);
  // Gather C: km1=0 from xb2.
  glaunch(NODES, xb2, agC0, agC0, agC0);
  // Layer 2: k=1 -> agC0 (xb2), k=2 -> agB1 (xb1), k=3 -> agA2 (xb0).
  hipLaunchKernelGGL(lgemm_kernel, dim3(ggrid), dim3(256), 0, stream,
                     xb2, agC0, agB1, agA2, WT, bs + 256, bk + 6 * 128, eps + 2,
                     (__hip_bfloat16*)nullptr, out, 2);
}